// Round 10
// baseline (2037.485 us; speedup 1.0000x reference)
//
#include <hip/hip_runtime.h>

#define DIM 128
#define NITERS 4

typedef _Float16 f16x8 __attribute__((ext_vector_type(8)));
typedef _Float16 f16x4 __attribute__((ext_vector_type(4)));
typedef _Float16 f16x2 __attribute__((ext_vector_type(2)));
typedef float f32x4 __attribute__((ext_vector_type(4)));

#define MFMA16(a, b, c) __builtin_amdgcn_mfma_f32_16x16x32_f16((a), (b), (c), 0, 0, 0)

__device__ __forceinline__ float sigmoidf_(float x) { return 1.f / (1.f + __expf(-x)); }
__device__ __forceinline__ float tanhf_(float x) { return 1.f - 2.f / (__expf(2.f * x) + 1.f); }

struct ConvDesc { const float* s; _Float16* d; int n; };

__global__ __launch_bounds__(256) void conv8_kernel(ConvDesc c0, ConvDesc c1, ConvDesc c2, ConvDesc c3,
                                                    ConvDesc c4, ConvDesc c5, ConvDesc c6, ConvDesc c7) {
    ConvDesc cd;
    switch (blockIdx.y) {
        case 0: cd = c0; break; case 1: cd = c1; break; case 2: cd = c2; break; case 3: cd = c3; break;
        case 4: cd = c4; break; case 5: cd = c5; break; case 6: cd = c6; break; default: cd = c7; break;
    }
    int i = blockIdx.x * 256 + threadIdx.x;
    if (i < cd.n) cd.d[i] = (_Float16)cd.s[i];
}

// copy f32 src -> f32 out slice (non-temporal; never re-read) AND f16 mirror (cached)
__global__ __launch_bounds__(256) void init_state_kernel(const float* __restrict__ src,
                                                         float* __restrict__ out32,
                                                         _Float16* __restrict__ out16, int n4) {
    int i = blockIdx.x * 256 + threadIdx.x;
    if (i >= n4) return;
    f32x4 v = ((const f32x4*)src)[i];
    __builtin_nontemporal_store(v, (f32x4*)out32 + i);
    f16x4 h; h[0] = (_Float16)v[0]; h[1] = (_Float16)v[1]; h[2] = (_Float16)v[2]; h[3] = (_Float16)v[3];
    ((f16x4*)out16)[i] = h;
}

// ---------------- CSR build (once per launch) ----------------

__global__ __launch_bounds__(256) void hist_both(const int* __restrict__ cE, int* __restrict__ degC,
                                                 const int* __restrict__ lE, int* __restrict__ degL,
                                                 int n, int eb) {
    if ((int)blockIdx.x < eb) {
        int i = blockIdx.x * 256 + threadIdx.x;
        if (i < n) atomicAdd(degC + cE[i], 1);
    } else {
        int i = (blockIdx.x - eb) * 256 + threadIdx.x;
        if (i < n) atomicAdd(degL + lE[i], 1);
    }
}

__global__ __launch_bounds__(256) void scan_reduce_both(const int* __restrict__ degC, int* __restrict__ bsC, int nC, int nbC,
                                                        const int* __restrict__ degL, int* __restrict__ bsL, int nL) {
    __shared__ int sh[256];
    const int t = threadIdx.x;
    const int* deg; int* bs; int n, b;
    if ((int)blockIdx.x < nbC) { deg = degC; bs = bsC; n = nC; b = blockIdx.x; }
    else { deg = degL; bs = bsL; n = nL; b = blockIdx.x - nbC; }
    const int base = b * 1024 + t * 4;
    int v = 0;
    #pragma unroll
    for (int k = 0; k < 4; ++k) { int i = base + k; if (i < n) v += deg[i]; }
    sh[t] = v; __syncthreads();
    for (int off = 128; off > 0; off >>= 1) {
        if (t < off) sh[t] += sh[t + off];
        __syncthreads();
    }
    if (t == 0) bs[b] = sh[0];
}

__global__ __launch_bounds__(256) void scan_blocksums_both(int* __restrict__ bsC, int nbC,
                                                           int* __restrict__ bsL, int nbL) {
    __shared__ int sh[256];
    int* bs = blockIdx.x == 0 ? bsC : bsL;
    int nb = blockIdx.x == 0 ? nbC : nbL;
    const int t = threadIdx.x;
    int v = (t < nb) ? bs[t] : 0;
    sh[t] = v; __syncthreads();
    for (int off = 1; off < 256; off <<= 1) {
        int u = (t >= off) ? sh[t - off] : 0;
        __syncthreads();
        sh[t] += u;
        __syncthreads();
    }
    if (t < nb) bs[t] = sh[t] - v;
}

__global__ __launch_bounds__(256) void scan_write_both(const int* __restrict__ degC, const int* __restrict__ bsC,
                                                       int* __restrict__ rsC, int nC, int nbC,
                                                       const int* __restrict__ degL, const int* __restrict__ bsL,
                                                       int* __restrict__ rsL, int nL) {
    __shared__ int sh[256];
    const int t = threadIdx.x;
    const int *deg, *bs; int *rs; int n, b;
    if ((int)blockIdx.x < nbC) { deg = degC; bs = bsC; rs = rsC; n = nC; b = blockIdx.x; }
    else { deg = degL; bs = bsL; rs = rsL; n = nL; b = blockIdx.x - nbC; }
    const int base = b * 1024 + t * 4;
    int v[4], p[4], s = 0;
    #pragma unroll
    for (int k = 0; k < 4; ++k) {
        int i = base + k;
        v[k] = (i < n) ? deg[i] : 0;
        p[k] = s; s += v[k];
    }
    sh[t] = s; __syncthreads();
    for (int off = 1; off < 256; off <<= 1) {
        int u = (t >= off) ? sh[t - off] : 0;
        __syncthreads();
        sh[t] += u;
        __syncthreads();
    }
    int off0 = bs[b] + (sh[t] - s);
    #pragma unroll
    for (int k = 0; k < 4; ++k) {
        int i = base + k;
        if (i < n) rs[i] = off0 + p[k];
    }
}

__global__ void set2_kernel(int* p0, int* p1, int v) { *p0 = v; *p1 = v; }

__global__ __launch_bounds__(256) void fill_both(const int* __restrict__ cE, const int* __restrict__ lE,
                                                 const int* __restrict__ rsC, int* __restrict__ curC, int* __restrict__ csrC,
                                                 const int* __restrict__ rsL, int* __restrict__ curL, int* __restrict__ csrL,
                                                 int n, int eb) {
    if ((int)blockIdx.x < eb) {
        int e = blockIdx.x * 256 + threadIdx.x;
        if (e >= n) return;
        int d = cE[e];
        int slot = atomicAdd(curC + d, 1);
        csrC[rsC[d] + slot] = lE[e];
    } else {
        int e = (blockIdx.x - eb) * 256 + threadIdx.x;
        if (e >= n) return;
        int d = lE[e];
        int slot = atomicAdd(curL + d, 1);
        csrL[rsL[d] + slot] = cE[e];
    }
}

// ---------------- pull-based aggregation (both directions, one dispatch) ----------------
// masked unroll-4: ALWAYS issue 4 parallel msg loads (dup index past end) -> dependent-chain
// depth = ceil(deg/4) instead of deg.
__global__ __launch_bounds__(256) void gather_both(
    const _Float16* __restrict__ msgA, const int* __restrict__ rsA, const int* __restrict__ csrA,
    _Float16* __restrict__ outA, int nA, int blkA,
    const _Float16* __restrict__ msgB, const int* __restrict__ rsB, const int* __restrict__ csrB,
    _Float16* __restrict__ outB, int nB)
{
    const int lane = threadIdx.x & 63;
    const int wave = threadIdx.x >> 6;
    const _Float16* msg; const int *rs, *csr; _Float16* out; int n, d;
    if ((int)blockIdx.x < blkA) { msg = msgA; rs = rsA; csr = csrA; out = outA; n = nA; d = blockIdx.x * 4 + wave; }
    else { msg = msgB; rs = rsB; csr = csrB; out = outB; n = nB; d = (blockIdx.x - blkA) * 4 + wave; }
    if (d >= n) return;
    const int beg = rs[d], end = rs[d + 1];
    float ax = 0.f, ay = 0.f, bx = 0.f, by = 0.f, cx = 0.f, cy = 0.f, dx = 0.f, dy = 0.f;
    const int col = lane * 2;
    for (int j = beg; j < end; j += 4) {
        const int rem = end - j;                    // wave-uniform
        int s0 = csr[j];
        int s1 = rem > 1 ? csr[j + 1] : s0;
        int s2 = rem > 2 ? csr[j + 2] : s0;
        int s3 = rem > 3 ? csr[j + 3] : s0;
        f16x2 v0 = *(const f16x2*)(msg + (size_t)s0 * DIM + col);
        f16x2 v1 = *(const f16x2*)(msg + (size_t)s1 * DIM + col);
        f16x2 v2 = *(const f16x2*)(msg + (size_t)s2 * DIM + col);
        f16x2 v3 = *(const f16x2*)(msg + (size_t)s3 * DIM + col);
        ax += (float)v0[0]; ay += (float)v0[1];
        if (rem > 1) { bx += (float)v1[0]; by += (float)v1[1]; }
        if (rem > 2) { cx += (float)v2[0]; cy += (float)v2[1]; }
        if (rem > 3) { dx += (float)v3[0]; dy += (float)v3[1]; }
    }
    float ox = (ax + bx) + (cx + dx), oy = (ay + by) + (cy + dy);
    f16x2 o; o[0] = (_Float16)ox; o[1] = (_Float16)oy;
    *(f16x2*)(out + (size_t)d * DIM + col) = o;
}

// ---------------- weight-stationary GRU, both node types, one dispatch ----------------
// 512 threads = 8 waves; wave w owns output cols [16w,16w+16); weights in VGPRs for the
// whole kernel. 16-row tiles. f32 outputs via non-temporal stores. do_mir=0 skips the
// f16 mirror write (last iteration: mirror never read again).
__global__ __launch_bounds__(512, 2) void gru_both_ws(
    const _Float16* __restrict__ Xc, const _Float16* __restrict__ Chm,
    const _Float16* __restrict__ cWih, const _Float16* __restrict__ cWhh,
    const float* __restrict__ cbih, const float* __restrict__ cbhh,
    float* __restrict__ Cout, _Float16* __restrict__ Cmir, int CTiles, int CBLK,
    const _Float16* __restrict__ Xl, const _Float16* __restrict__ Lhm,
    const _Float16* __restrict__ lWih, const _Float16* __restrict__ lWhh,
    const float* __restrict__ lbih, const float* __restrict__ lbhh,
    float* __restrict__ Lout, _Float16* __restrict__ Lmir, int LTiles, int do_mir)
{
    const int lane = threadIdx.x & 63;
    const int wave = threadIdx.x >> 6;
    const int l15 = lane & 15;
    const int kg  = lane >> 4;
    const int col = wave * 16 + l15;

    if ((int)blockIdx.x < CBLK) {
        // ---- clause GRU: x = l2c_aggr (K=128), h = C mirror ----
        f16x8 wi[3][4], wh[3][4];
        #pragma unroll
        for (int g = 0; g < 3; ++g)
            #pragma unroll
            for (int kk = 0; kk < 4; ++kk) {
                wi[g][kk] = *(const f16x8*)(cWih + (size_t)(g * 128 + col) * DIM + kg * 8 + kk * 32);
                wh[g][kk] = *(const f16x8*)(cWhh + (size_t)(g * 128 + col) * DIM + kg * 8 + kk * 32);
            }
        const float brc = cbih[col] + cbhh[col];
        const float bzc = cbih[128 + col] + cbhh[128 + col];
        const float bgn = cbih[256 + col];
        const float bhn = cbhh[256 + col];
        for (int tile = blockIdx.x; tile < CTiles; tile += CBLK) {
            const size_t r0 = (size_t)tile * 16;
            f16x8 xa[4], ha[4];
            float h4[4];
            const _Float16* xp = Xc  + (r0 + l15) * DIM + kg * 8;
            const _Float16* hp = Chm + (r0 + l15) * DIM + kg * 8;
            #pragma unroll
            for (int kk = 0; kk < 4; ++kk) {
                xa[kk] = *(const f16x8*)(xp + kk * 32);
                ha[kk] = *(const f16x8*)(hp + kk * 32);
            }
            #pragma unroll
            for (int r = 0; r < 4; ++r)
                h4[r] = (float)Chm[(r0 + kg * 4 + r) * DIM + col];
            f32x4 ar = {0,0,0,0}, az = {0,0,0,0}, an = {0,0,0,0}, ah = {0,0,0,0};
            #pragma unroll
            for (int kk = 0; kk < 4; ++kk) {
                ar = MFMA16(xa[kk], wi[0][kk], ar);
                ar = MFMA16(ha[kk], wh[0][kk], ar);
                az = MFMA16(xa[kk], wi[1][kk], az);
                az = MFMA16(ha[kk], wh[1][kk], az);
                an = MFMA16(xa[kk], wi[2][kk], an);
                ah = MFMA16(ha[kk], wh[2][kk], ah);
            }
            #pragma unroll
            for (int r = 0; r < 4; ++r) {
                size_t row = r0 + kg * 4 + r;
                float rg = sigmoidf_(ar[r] + brc);
                float zg = sigmoidf_(az[r] + bzc);
                float ng = tanhf_(an[r] + bgn + rg * (ah[r] + bhn));
                float o = (1.f - zg) * ng + zg * h4[r];
                __builtin_nontemporal_store(o, &Cout[row * DIM + col]);
                if (do_mir) Cmir[row * DIM + col] = (_Float16)o;
            }
        }
    } else {
        // ---- literal GRU: x = concat(c2l_aggr, L[row^1]) (K=256), h = L mirror ----
        const int LBLK = gridDim.x - CBLK;
        f16x8 wi[3][8], wh[3][4];
        #pragma unroll
        for (int g = 0; g < 3; ++g) {
            #pragma unroll
            for (int kk = 0; kk < 8; ++kk)
                wi[g][kk] = *(const f16x8*)(lWih + (size_t)(g * 128 + col) * 256 + kg * 8 + kk * 32);
            #pragma unroll
            for (int kk = 0; kk < 4; ++kk)
                wh[g][kk] = *(const f16x8*)(lWhh + (size_t)(g * 128 + col) * DIM + kg * 8 + kk * 32);
        }
        const float brc = lbih[col] + lbhh[col];
        const float bzc = lbih[128 + col] + lbhh[128 + col];
        const float bgn = lbih[256 + col];
        const float bhn = lbhh[256 + col];
        for (int tile = blockIdx.x - CBLK; tile < LTiles; tile += LBLK) {
            const size_t r0 = (size_t)tile * 16;
            f16x8 xa[4], xs[4], ha[4];
            float h4[4];
            const _Float16* xp = Xl  + (r0 + l15) * DIM + kg * 8;
            const _Float16* hp = Lhm + (r0 + l15) * DIM + kg * 8;
            const _Float16* sp = Lhm + ((r0 + l15) ^ 1) * DIM + kg * 8;
            #pragma unroll
            for (int kk = 0; kk < 4; ++kk) {
                xa[kk] = *(const f16x8*)(xp + kk * 32);
                xs[kk] = *(const f16x8*)(sp + kk * 32);
                ha[kk] = *(const f16x8*)(hp + kk * 32);
            }
            #pragma unroll
            for (int r = 0; r < 4; ++r)
                h4[r] = (float)Lhm[(r0 + kg * 4 + r) * DIM + col];
            f32x4 ar = {0,0,0,0}, az = {0,0,0,0}, an = {0,0,0,0}, ah = {0,0,0,0};
            #pragma unroll
            for (int kk = 0; kk < 4; ++kk) {
                ar = MFMA16(xa[kk], wi[0][kk],     ar);
                ar = MFMA16(xs[kk], wi[0][kk + 4], ar);
                ar = MFMA16(ha[kk], wh[0][kk],     ar);
                az = MFMA16(xa[kk], wi[1][kk],     az);
                az = MFMA16(xs[kk], wi[1][kk + 4], az);
                az = MFMA16(ha[kk], wh[1][kk],     az);
                an = MFMA16(xa[kk], wi[2][kk],     an);
                an = MFMA16(xs[kk], wi[2][kk + 4], an);
                ah = MFMA16(ha[kk], wh[2][kk],     ah);
            }
            #pragma unroll
            for (int r = 0; r < 4; ++r) {
                size_t row = r0 + kg * 4 + r;
                float rg = sigmoidf_(ar[r] + brc);
                float zg = sigmoidf_(az[r] + bzc);
                float ng = tanhf_(an[r] + bgn + rg * (ah[r] + bhn));
                float o = (1.f - zg) * ng + zg * h4[r];
                __builtin_nontemporal_store(o, &Lout[row * DIM + col]);
                if (do_mir) Lmir[row * DIM + col] = (_Float16)o;
            }
        }
    }
}

// ---------------- weight-stationary message MLP, both node types ----------------
__global__ __launch_bounds__(512, 4) void mlp_both_ws(
    const _Float16* __restrict__ XL, const _Float16* __restrict__ lW1, const float* __restrict__ lB1,
    const _Float16* __restrict__ lW2, const float* __restrict__ lB2, _Float16* __restrict__ MsgL,
    int LTiles, int LBLK,
    const _Float16* __restrict__ XC, const _Float16* __restrict__ cW1, const float* __restrict__ cB1,
    const _Float16* __restrict__ cW2, const float* __restrict__ cB2, _Float16* __restrict__ MsgC,
    int CTiles)
{
    __shared__ _Float16 hid[2][16][136];
    const int lane = threadIdx.x & 63;
    const int wave = threadIdx.x >> 6;
    const int l15 = lane & 15;
    const int kg  = lane >> 4;
    const int col = wave * 16 + l15;

    const _Float16 *X, *W1, *W2; const float *B1p, *B2p; _Float16* Msg;
    int tiles, t0, stride;
    if ((int)blockIdx.x < LBLK) {
        X = XL; W1 = lW1; B1p = lB1; W2 = lW2; B2p = lB2; Msg = MsgL;
        tiles = LTiles; t0 = blockIdx.x; stride = LBLK;
    } else {
        X = XC; W1 = cW1; B1p = cB1; W2 = cW2; B2p = cB2; Msg = MsgC;
        tiles = CTiles; t0 = blockIdx.x - LBLK; stride = gridDim.x - LBLK;
    }
    f16x8 w1[4], w2[4];
    #pragma unroll
    for (int kk = 0; kk < 4; ++kk) {
        w1[kk] = *(const f16x8*)(W1 + (size_t)col * DIM + kg * 8 + kk * 32);
        w2[kk] = *(const f16x8*)(W2 + (size_t)col * DIM + kg * 8 + kk * 32);
    }
    const float b1 = B1p[col], b2 = B2p[col];
    int buf = 0;
    for (int tile = t0; tile < tiles; tile += stride) {
        const size_t r0 = (size_t)tile * 16;
        f16x8 xa[4];
        const _Float16* xp = X + (r0 + l15) * DIM + kg * 8;
        #pragma unroll
        for (int kk = 0; kk < 4; ++kk) xa[kk] = *(const f16x8*)(xp + kk * 32);
        f32x4 a1 = {0,0,0,0};
        #pragma unroll
        for (int kk = 0; kk < 4; ++kk) a1 = MFMA16(xa[kk], w1[kk], a1);
        #pragma unroll
        for (int r = 0; r < 4; ++r) {
            float v = a1[r] + b1;
            hid[buf][kg * 4 + r][col] = (_Float16)(v > 0.f ? v : 0.f);
        }
        __syncthreads();
        f16x8 h2[4];
        #pragma unroll
        for (int kk = 0; kk < 4; ++kk)
            h2[kk] = *(const f16x8*)(&hid[buf][l15][kk * 32 + kg * 8]);
        f32x4 a2 = {0,0,0,0};
        #pragma unroll
        for (int kk = 0; kk < 4; ++kk) a2 = MFMA16(h2[kk], w2[kk], a2);
        #pragma unroll
        for (int r = 0; r < 4; ++r)
            Msg[(r0 + kg * 4 + r) * DIM + col] = (_Float16)(a2[r] + b2);
        buf ^= 1;
    }
}

extern "C" void kernel_launch(void* const* d_in, const int* in_sizes, int n_in,
                              void* d_out, int out_size, void* d_ws, size_t ws_size,
                              hipStream_t stream)
{
    const int*   l_edge = (const int*)d_in[2];
    const int*   c_edge = (const int*)d_in[3];
    const float* l_emb0 = (const float*)d_in[4];
    const float* c_emb0 = (const float*)d_in[5];
    const float* l2c_w1 = (const float*)d_in[6];
    const float* l2c_b1 = (const float*)d_in[7];
    const float* l2c_w2 = (const float*)d_in[8];
    const float* l2c_b2 = (const float*)d_in[9];
    const float* c2l_w1 = (const float*)d_in[10];
    const float* c2l_b1 = (const float*)d_in[11];
    const float* c2l_w2 = (const float*)d_in[12];
    const float* c2l_b2 = (const float*)d_in[13];
    const float* c_w_ih = (const float*)d_in[14];
    const float* c_w_hh = (const float*)d_in[15];
    const float* c_b_ih = (const float*)d_in[16];
    const float* c_b_hh = (const float*)d_in[17];
    const float* l_w_ih = (const float*)d_in[18];
    const float* l_w_hh = (const float*)d_in[19];
    const float* l_b_ih = (const float*)d_in[20];
    const float* l_b_hh = (const float*)d_in[21];

    const int n_edges = in_sizes[2];
    const int Lsz = in_sizes[4] / DIM;   // 80000
    const int Csz = in_sizes[5] / DIM;   // 160000

    float* OUT_L = (float*)d_out;                                  // (5, Lsz, 128)
    float* OUT_C = OUT_L + (size_t)(NITERS + 1) * Lsz * DIM;       // (5, Csz, 128)

    char* wsp = (char*)d_ws;
    auto carve = [&](size_t bytes) -> void* {
        void* p = (void*)wsp;
        wsp += (bytes + 255) & ~(size_t)255;
        return p;
    };
    _Float16* c_msg    = (_Float16*)carve((size_t)Csz * DIM * 2);
    _Float16* l_msg    = (_Float16*)carve((size_t)Lsz * DIM * 2);
    _Float16* l2c_aggr = (_Float16*)carve((size_t)Csz * DIM * 2);
    _Float16* c2l_aggr = (_Float16*)carve((size_t)Lsz * DIM * 2);
    _Float16* Ch0      = (_Float16*)carve((size_t)Csz * DIM * 2);
    _Float16* Ch1      = (_Float16*)carve((size_t)Csz * DIM * 2);
    _Float16* Lh0      = (_Float16*)carve((size_t)Lsz * DIM * 2);
    _Float16* Lh1      = (_Float16*)carve((size_t)Lsz * DIM * 2);
    int* deg_c = (int*)carve((size_t)(Csz)     * 4);   // deg_c|deg_l|cur_c|cur_l contiguous: one memset
    int* deg_l = (int*)carve((size_t)(Lsz)     * 4);
    int* cur_c = (int*)carve((size_t)(Csz)     * 4);
    int* cur_l = (int*)carve((size_t)(Lsz)     * 4);
    int* rs_c  = (int*)carve((size_t)(Csz + 1) * 4);
    int* rs_l  = (int*)carve((size_t)(Lsz + 1) * 4);
    int* csr_c = (int*)carve((size_t)n_edges   * 4);
    int* csr_l = (int*)carve((size_t)n_edges   * 4);
    int* bsum_c = (int*)carve(256 * 4);
    int* bsum_l = (int*)carve(256 * 4);
    _Float16* hw_l2c1 = (_Float16*)carve((size_t)DIM * DIM * 2);
    _Float16* hw_l2c2 = (_Float16*)carve((size_t)DIM * DIM * 2);
    _Float16* hw_c2l1 = (_Float16*)carve((size_t)DIM * DIM * 2);
    _Float16* hw_c2l2 = (_Float16*)carve((size_t)DIM * DIM * 2);
    _Float16* hw_cih  = (_Float16*)carve((size_t)3 * DIM * DIM * 2);
    _Float16* hw_chh  = (_Float16*)carve((size_t)3 * DIM * DIM * 2);
    _Float16* hw_lih  = (_Float16*)carve((size_t)3 * DIM * 2 * DIM * 2);
    _Float16* hw_lhh  = (_Float16*)carve((size_t)3 * DIM * DIM * 2);

    {
        ConvDesc cds[8] = {
            { l2c_w1, hw_l2c1, DIM * DIM }, { l2c_w2, hw_l2c2, DIM * DIM },
            { c2l_w1, hw_c2l1, DIM * DIM }, { c2l_w2, hw_c2l2, DIM * DIM },
            { c_w_ih, hw_cih, 3 * DIM * DIM }, { c_w_hh, hw_chh, 3 * DIM * DIM },
            { l_w_ih, hw_lih, 3 * DIM * 2 * DIM }, { l_w_hh, hw_lhh, 3 * DIM * DIM },
        };
        conv8_kernel<<<dim3(384, 8), 256, 0, stream>>>(cds[0], cds[1], cds[2], cds[3],
                                                       cds[4], cds[5], cds[6], cds[7]);
    }

    init_state_kernel<<<(Lsz * DIM / 4 + 255) / 256, 256, 0, stream>>>(l_emb0, OUT_L, Lh0, Lsz * DIM / 4);
    init_state_kernel<<<(Csz * DIM / 4 + 255) / 256, 256, 0, stream>>>(c_emb0, OUT_C, Ch0, Csz * DIM / 4);

    // ---- CSR build (both directions) ----
    hipMemsetAsync(deg_c, 0, (size_t)(2 * Csz + 2 * Lsz) * 4, stream);

    const int eb = (n_edges + 255) / 256;
    hist_both<<<2 * eb, 256, 0, stream>>>(c_edge, deg_c, l_edge, deg_l, n_edges, eb);

    const int nb_c = (Csz + 1023) / 1024;
    const int nb_l = (Lsz + 1023) / 1024;
    scan_reduce_both<<<nb_c + nb_l, 256, 0, stream>>>(deg_c, bsum_c, Csz, nb_c, deg_l, bsum_l, Lsz);
    scan_blocksums_both<<<2, 256, 0, stream>>>(bsum_c, nb_c, bsum_l, nb_l);
    scan_write_both<<<nb_c + nb_l, 256, 0, stream>>>(deg_c, bsum_c, rs_c, Csz, nb_c, deg_l, bsum_l, rs_l, Lsz);
    set2_kernel<<<1, 1, 0, stream>>>(rs_c + Csz, rs_l + Lsz, n_edges);
    fill_both<<<2 * eb, 256, 0, stream>>>(c_edge, l_edge, rs_c, cur_c, csr_c, rs_l, cur_l, csr_l, n_edges, eb);

    const int LTiles = Lsz / 16, CTiles = Csz / 16;
    const int MLP_LBLK = 340, MLP_GRID = 1024;
    const int GRU_CBLK = 150, GRU_GRID = 256;
    const int GATH_BLKA = (Csz + 3) / 4;
    const int GATH_GRID = GATH_BLKA + (Lsz + 3) / 4;

    // prologue messages from initial state
    mlp_both_ws<<<MLP_GRID, 512, 0, stream>>>(Lh0, hw_l2c1, l2c_b1, hw_l2c2, l2c_b2, l_msg, LTiles, MLP_LBLK,
                                              Ch0, hw_c2l1, c2l_b1, hw_c2l2, c2l_b2, c_msg, CTiles);

    for (int t = 0; t < NITERS; ++t) {
        float* Lt1 = OUT_L + (size_t)(t + 1) * Lsz * DIM;
        float* Ct1 = OUT_C + (size_t)(t + 1) * Csz * DIM;
        const _Float16* Lm = (t & 1) ? Lh1 : Lh0;
        const _Float16* Cm = (t & 1) ? Ch1 : Ch0;
        _Float16* Lm1 = (t & 1) ? Lh0 : Lh1;
        _Float16* Cm1 = (t & 1) ? Ch0 : Ch1;
        const int do_mir = (t < NITERS - 1) ? 1 : 0;

        // MEASUREMENT: gather launched 3x (idempotent pure function).
        // dur' - base = 8 * per-gather-dispatch cost.
        for (int rep = 0; rep < 3; ++rep)
            gather_both<<<GATH_GRID, 256, 0, stream>>>(l_msg, rs_c, csr_c, l2c_aggr, Csz, GATH_BLKA,
                                                       c_msg, rs_l, csr_l, c2l_aggr, Lsz);
        gru_both_ws<<<GRU_GRID, 512, 0, stream>>>(l2c_aggr, Cm, hw_cih, hw_chh, c_b_ih, c_b_hh,
                                                  Ct1, Cm1, CTiles, GRU_CBLK,
                                                  c2l_aggr, Lm, hw_lih, hw_lhh, l_b_ih, l_b_hh,
                                                  Lt1, Lm1, LTiles, do_mir);
        if (t < NITERS - 1)
            mlp_both_ws<<<MLP_GRID, 512, 0, stream>>>(Lm1, hw_l2c1, l2c_b1, hw_l2c2, l2c_b2, l_msg, LTiles, MLP_LBLK,
                                                      Cm1, hw_c2l1, c2l_b1, hw_c2l2, c2l_b2, c_msg, CTiles);
    }
}

// Round 11
// 1411.401 us; speedup vs baseline: 1.4436x; 1.4436x over previous
//
#include <hip/hip_runtime.h>

#define DIM 128
#define NITERS 4

typedef _Float16 f16x8 __attribute__((ext_vector_type(8)));
typedef _Float16 f16x4 __attribute__((ext_vector_type(4)));
typedef _Float16 f16x2 __attribute__((ext_vector_type(2)));
typedef float f32x4 __attribute__((ext_vector_type(4)));

#define MFMA16(a, b, c) __builtin_amdgcn_mfma_f32_16x16x32_f16((a), (b), (c), 0, 0, 0)

__device__ __forceinline__ float sigmoidf_(float x) { return 1.f / (1.f + __expf(-x)); }
__device__ __forceinline__ float tanhf_(float x) { return 1.f - 2.f / (__expf(2.f * x) + 1.f); }

// lane^1 exchange of a 16-byte fragment (compiler lowers to DPP quad-perm)
__device__ __forceinline__ f16x8 shfl_xor1(f16x8 v) {
    union { f16x8 h; int i[4]; } u; u.h = v;
    #pragma unroll
    for (int k = 0; k < 4; ++k) u.i[k] = __shfl_xor(u.i[k], 1);
    return u.h;
}

struct ConvDesc { const float* s; _Float16* d; int n; };

__global__ __launch_bounds__(256) void conv8_kernel(ConvDesc c0, ConvDesc c1, ConvDesc c2, ConvDesc c3,
                                                    ConvDesc c4, ConvDesc c5, ConvDesc c6, ConvDesc c7) {
    ConvDesc cd;
    switch (blockIdx.y) {
        case 0: cd = c0; break; case 1: cd = c1; break; case 2: cd = c2; break; case 3: cd = c3; break;
        case 4: cd = c4; break; case 5: cd = c5; break; case 6: cd = c6; break; default: cd = c7; break;
    }
    int i = blockIdx.x * 256 + threadIdx.x;
    if (i < cd.n) cd.d[i] = (_Float16)cd.s[i];
}

// copy f32 src -> f32 out slice (non-temporal; never re-read) AND f16 mirror (cached)
__global__ __launch_bounds__(256) void init_state_kernel(const float* __restrict__ src,
                                                         float* __restrict__ out32,
                                                         _Float16* __restrict__ out16, int n4) {
    int i = blockIdx.x * 256 + threadIdx.x;
    if (i >= n4) return;
    f32x4 v = ((const f32x4*)src)[i];
    __builtin_nontemporal_store(v, (f32x4*)out32 + i);
    f16x4 h; h[0] = (_Float16)v[0]; h[1] = (_Float16)v[1]; h[2] = (_Float16)v[2]; h[3] = (_Float16)v[3];
    ((f16x4*)out16)[i] = h;
}

// ---------------- CSR build (once per launch) ----------------

__global__ __launch_bounds__(256) void hist_both(const int* __restrict__ cE, int* __restrict__ degC,
                                                 const int* __restrict__ lE, int* __restrict__ degL,
                                                 int n, int eb) {
    if ((int)blockIdx.x < eb) {
        int i = blockIdx.x * 256 + threadIdx.x;
        if (i < n) atomicAdd(degC + cE[i], 1);
    } else {
        int i = (blockIdx.x - eb) * 256 + threadIdx.x;
        if (i < n) atomicAdd(degL + lE[i], 1);
    }
}

__global__ __launch_bounds__(256) void scan_reduce_both(const int* __restrict__ degC, int* __restrict__ bsC, int nC, int nbC,
                                                        const int* __restrict__ degL, int* __restrict__ bsL, int nL) {
    __shared__ int sh[256];
    const int t = threadIdx.x;
    const int* deg; int* bs; int n, b;
    if ((int)blockIdx.x < nbC) { deg = degC; bs = bsC; n = nC; b = blockIdx.x; }
    else { deg = degL; bs = bsL; n = nL; b = blockIdx.x - nbC; }
    const int base = b * 1024 + t * 4;
    int v = 0;
    #pragma unroll
    for (int k = 0; k < 4; ++k) { int i = base + k; if (i < n) v += deg[i]; }
    sh[t] = v; __syncthreads();
    for (int off = 128; off > 0; off >>= 1) {
        if (t < off) sh[t] += sh[t + off];
        __syncthreads();
    }
    if (t == 0) bs[b] = sh[0];
}

__global__ __launch_bounds__(256) void scan_blocksums_both(int* __restrict__ bsC, int nbC,
                                                           int* __restrict__ bsL, int nbL) {
    __shared__ int sh[256];
    int* bs = blockIdx.x == 0 ? bsC : bsL;
    int nb = blockIdx.x == 0 ? nbC : nbL;
    const int t = threadIdx.x;
    int v = (t < nb) ? bs[t] : 0;
    sh[t] = v; __syncthreads();
    for (int off = 1; off < 256; off <<= 1) {
        int u = (t >= off) ? sh[t - off] : 0;
        __syncthreads();
        sh[t] += u;
        __syncthreads();
    }
    if (t < nb) bs[t] = sh[t] - v;
}

__global__ __launch_bounds__(256) void scan_write_both(const int* __restrict__ degC, const int* __restrict__ bsC,
                                                       int* __restrict__ rsC, int nC, int nbC,
                                                       const int* __restrict__ degL, const int* __restrict__ bsL,
                                                       int* __restrict__ rsL, int nL) {
    __shared__ int sh[256];
    const int t = threadIdx.x;
    const int *deg, *bs; int *rs; int n, b;
    if ((int)blockIdx.x < nbC) { deg = degC; bs = bsC; rs = rsC; n = nC; b = blockIdx.x; }
    else { deg = degL; bs = bsL; rs = rsL; n = nL; b = blockIdx.x - nbC; }
    const int base = b * 1024 + t * 4;
    int v[4], p[4], s = 0;
    #pragma unroll
    for (int k = 0; k < 4; ++k) {
        int i = base + k;
        v[k] = (i < n) ? deg[i] : 0;
        p[k] = s; s += v[k];
    }
    sh[t] = s; __syncthreads();
    for (int off = 1; off < 256; off <<= 1) {
        int u = (t >= off) ? sh[t - off] : 0;
        __syncthreads();
        sh[t] += u;
        __syncthreads();
    }
    int off0 = bs[b] + (sh[t] - s);
    #pragma unroll
    for (int k = 0; k < 4; ++k) {
        int i = base + k;
        if (i < n) rs[i] = off0 + p[k];
    }
}

__global__ void set2_kernel(int* p0, int* p1, int v) { *p0 = v; *p1 = v; }

__global__ __launch_bounds__(256) void fill_both(const int* __restrict__ cE, const int* __restrict__ lE,
                                                 const int* __restrict__ rsC, int* __restrict__ curC, int* __restrict__ csrC,
                                                 const int* __restrict__ rsL, int* __restrict__ curL, int* __restrict__ csrL,
                                                 int n, int eb) {
    if ((int)blockIdx.x < eb) {
        int e = blockIdx.x * 256 + threadIdx.x;
        if (e >= n) return;
        int d = cE[e];
        int slot = atomicAdd(curC + d, 1);
        csrC[rsC[d] + slot] = lE[e];
    } else {
        int e = (blockIdx.x - eb) * 256 + threadIdx.x;
        if (e >= n) return;
        int d = lE[e];
        int slot = atomicAdd(curL + d, 1);
        csrL[rsL[d] + slot] = cE[e];
    }
}

// ---------------- pull-based aggregation (both directions, one dispatch) ----------------
// masked unroll-4: ALWAYS issue 4 parallel msg loads (dup index past end) -> dependent-chain
// depth = ceil(deg/4) instead of deg.
__global__ __launch_bounds__(256) void gather_both(
    const _Float16* __restrict__ msgA, const int* __restrict__ rsA, const int* __restrict__ csrA,
    _Float16* __restrict__ outA, int nA, int blkA,
    const _Float16* __restrict__ msgB, const int* __restrict__ rsB, const int* __restrict__ csrB,
    _Float16* __restrict__ outB, int nB)
{
    const int lane = threadIdx.x & 63;
    const int wave = threadIdx.x >> 6;
    const _Float16* msg; const int *rs, *csr; _Float16* out; int n, d;
    if ((int)blockIdx.x < blkA) { msg = msgA; rs = rsA; csr = csrA; out = outA; n = nA; d = blockIdx.x * 4 + wave; }
    else { msg = msgB; rs = rsB; csr = csrB; out = outB; n = nB; d = (blockIdx.x - blkA) * 4 + wave; }
    if (d >= n) return;
    const int beg = rs[d], end = rs[d + 1];
    float ax = 0.f, ay = 0.f, bx = 0.f, by = 0.f, cx = 0.f, cy = 0.f, dx = 0.f, dy = 0.f;
    const int col = lane * 2;
    for (int j = beg; j < end; j += 4) {
        const int rem = end - j;                    // wave-uniform
        int s0 = csr[j];
        int s1 = rem > 1 ? csr[j + 1] : s0;
        int s2 = rem > 2 ? csr[j + 2] : s0;
        int s3 = rem > 3 ? csr[j + 3] : s0;
        f16x2 v0 = *(const f16x2*)(msg + (size_t)s0 * DIM + col);
        f16x2 v1 = *(const f16x2*)(msg + (size_t)s1 * DIM + col);
        f16x2 v2 = *(const f16x2*)(msg + (size_t)s2 * DIM + col);
        f16x2 v3 = *(const f16x2*)(msg + (size_t)s3 * DIM + col);
        ax += (float)v0[0]; ay += (float)v0[1];
        if (rem > 1) { bx += (float)v1[0]; by += (float)v1[1]; }
        if (rem > 2) { cx += (float)v2[0]; cy += (float)v2[1]; }
        if (rem > 3) { dx += (float)v3[0]; dy += (float)v3[1]; }
    }
    float ox = (ax + bx) + (cx + dx), oy = (ay + by) + (cy + dy);
    f16x2 o; o[0] = (_Float16)ox; o[1] = (_Float16)oy;
    *(f16x2*)(out + (size_t)d * DIM + col) = o;
}

// ---------------- weight-stationary GRU, both node types, one dispatch ----------------
// 512 threads = 8 waves; wave w owns output cols [16w,16w+16); weights in VGPRs for the
// whole kernel. Clause branch: next-tile prefetch (free VGPRs — literal branch sets the
// kernel's register highwater). Literal branch: partner-row fragments via lane^1 shuffle.
__global__ __launch_bounds__(512, 2) void gru_both_ws(
    const _Float16* __restrict__ Xc, const _Float16* __restrict__ Chm,
    const _Float16* __restrict__ cWih, const _Float16* __restrict__ cWhh,
    const float* __restrict__ cbih, const float* __restrict__ cbhh,
    float* __restrict__ Cout, _Float16* __restrict__ Cmir, int CTiles, int CBLK,
    const _Float16* __restrict__ Xl, const _Float16* __restrict__ Lhm,
    const _Float16* __restrict__ lWih, const _Float16* __restrict__ lWhh,
    const float* __restrict__ lbih, const float* __restrict__ lbhh,
    float* __restrict__ Lout, _Float16* __restrict__ Lmir, int LTiles, int do_mir)
{
    const int lane = threadIdx.x & 63;
    const int wave = threadIdx.x >> 6;
    const int l15 = lane & 15;
    const int kg  = lane >> 4;
    const int col = wave * 16 + l15;

    if ((int)blockIdx.x < CBLK) {
        // ---- clause GRU: x = l2c_aggr (K=128), h = C mirror; pipelined tiles ----
        f16x8 wi[3][4], wh[3][4];
        #pragma unroll
        for (int g = 0; g < 3; ++g)
            #pragma unroll
            for (int kk = 0; kk < 4; ++kk) {
                wi[g][kk] = *(const f16x8*)(cWih + (size_t)(g * 128 + col) * DIM + kg * 8 + kk * 32);
                wh[g][kk] = *(const f16x8*)(cWhh + (size_t)(g * 128 + col) * DIM + kg * 8 + kk * 32);
            }
        const float brc = cbih[col] + cbhh[col];
        const float bzc = cbih[128 + col] + cbhh[128 + col];
        const float bgn = cbih[256 + col];
        const float bhn = cbhh[256 + col];
        int tile = blockIdx.x;
        f16x8 xa[4], ha[4];
        float h4[4];
        if (tile < CTiles) {
            const size_t r0 = (size_t)tile * 16;
            const _Float16* xp = Xc  + (r0 + l15) * DIM + kg * 8;
            const _Float16* hp = Chm + (r0 + l15) * DIM + kg * 8;
            #pragma unroll
            for (int kk = 0; kk < 4; ++kk) {
                xa[kk] = *(const f16x8*)(xp + kk * 32);
                ha[kk] = *(const f16x8*)(hp + kk * 32);
            }
            #pragma unroll
            for (int r = 0; r < 4; ++r)
                h4[r] = (float)Chm[(r0 + kg * 4 + r) * DIM + col];
        }
        while (tile < CTiles) {
            const int tn = tile + CBLK;
            const size_t r0 = (size_t)tile * 16;
            f32x4 ar = {0,0,0,0}, az = {0,0,0,0}, an = {0,0,0,0}, ah = {0,0,0,0};
            #pragma unroll
            for (int kk = 0; kk < 4; ++kk) {
                ar = MFMA16(xa[kk], wi[0][kk], ar);
                ar = MFMA16(ha[kk], wh[0][kk], ar);
                az = MFMA16(xa[kk], wi[1][kk], az);
                az = MFMA16(ha[kk], wh[1][kk], az);
                an = MFMA16(xa[kk], wi[2][kk], an);
                ah = MFMA16(ha[kk], wh[2][kk], ah);
            }
            // prefetch next tile while MFMA/pointwise retire
            f16x8 xb[4], hb[4];
            float h4b[4];
            if (tn < CTiles) {
                const size_t r1 = (size_t)tn * 16;
                const _Float16* xp = Xc  + (r1 + l15) * DIM + kg * 8;
                const _Float16* hp = Chm + (r1 + l15) * DIM + kg * 8;
                #pragma unroll
                for (int kk = 0; kk < 4; ++kk) {
                    xb[kk] = *(const f16x8*)(xp + kk * 32);
                    hb[kk] = *(const f16x8*)(hp + kk * 32);
                }
                #pragma unroll
                for (int r = 0; r < 4; ++r)
                    h4b[r] = (float)Chm[(r1 + kg * 4 + r) * DIM + col];
            }
            #pragma unroll
            for (int r = 0; r < 4; ++r) {
                size_t row = r0 + kg * 4 + r;
                float rg = sigmoidf_(ar[r] + brc);
                float zg = sigmoidf_(az[r] + bzc);
                float ng = tanhf_(an[r] + bgn + rg * (ah[r] + bhn));
                float o = (1.f - zg) * ng + zg * h4[r];
                __builtin_nontemporal_store(o, &Cout[row * DIM + col]);
                if (do_mir) Cmir[row * DIM + col] = (_Float16)o;
            }
            #pragma unroll
            for (int kk = 0; kk < 4; ++kk) { xa[kk] = xb[kk]; ha[kk] = hb[kk]; }
            #pragma unroll
            for (int r = 0; r < 4; ++r) h4[r] = h4b[r];
            tile = tn;
        }
    } else {
        // ---- literal GRU: x = concat(c2l_aggr, L[row^1]) (K=256), h = L mirror ----
        // partner-row fragments (row^1) come from the adjacent lane's ha via shuffle:
        // r0 is 16-aligned so (r0+l15)^1 = r0+(l15^1), i.e. lane^1's fragment.
        const int LBLK = gridDim.x - CBLK;
        f16x8 wi[3][8], wh[3][4];
        #pragma unroll
        for (int g = 0; g < 3; ++g) {
            #pragma unroll
            for (int kk = 0; kk < 8; ++kk)
                wi[g][kk] = *(const f16x8*)(lWih + (size_t)(g * 128 + col) * 256 + kg * 8 + kk * 32);
            #pragma unroll
            for (int kk = 0; kk < 4; ++kk)
                wh[g][kk] = *(const f16x8*)(lWhh + (size_t)(g * 128 + col) * DIM + kg * 8 + kk * 32);
        }
        const float brc = lbih[col] + lbhh[col];
        const float bzc = lbih[128 + col] + lbhh[128 + col];
        const float bgn = lbih[256 + col];
        const float bhn = lbhh[256 + col];
        for (int tile = blockIdx.x - CBLK; tile < LTiles; tile += LBLK) {
            const size_t r0 = (size_t)tile * 16;
            f16x8 xa[4], xs[4], ha[4];
            float h4[4];
            const _Float16* xp = Xl  + (r0 + l15) * DIM + kg * 8;
            const _Float16* hp = Lhm + (r0 + l15) * DIM + kg * 8;
            #pragma unroll
            for (int kk = 0; kk < 4; ++kk) {
                xa[kk] = *(const f16x8*)(xp + kk * 32);
                ha[kk] = *(const f16x8*)(hp + kk * 32);
            }
            #pragma unroll
            for (int kk = 0; kk < 4; ++kk)
                xs[kk] = shfl_xor1(ha[kk]);
            #pragma unroll
            for (int r = 0; r < 4; ++r)
                h4[r] = (float)Lhm[(r0 + kg * 4 + r) * DIM + col];
            f32x4 ar = {0,0,0,0}, az = {0,0,0,0}, an = {0,0,0,0}, ah = {0,0,0,0};
            #pragma unroll
            for (int kk = 0; kk < 4; ++kk) {
                ar = MFMA16(xa[kk], wi[0][kk],     ar);
                ar = MFMA16(xs[kk], wi[0][kk + 4], ar);
                ar = MFMA16(ha[kk], wh[0][kk],     ar);
                az = MFMA16(xa[kk], wi[1][kk],     az);
                az = MFMA16(xs[kk], wi[1][kk + 4], az);
                az = MFMA16(ha[kk], wh[1][kk],     az);
                an = MFMA16(xa[kk], wi[2][kk],     an);
                an = MFMA16(xs[kk], wi[2][kk + 4], an);
                ah = MFMA16(ha[kk], wh[2][kk],     ah);
            }
            #pragma unroll
            for (int r = 0; r < 4; ++r) {
                size_t row = r0 + kg * 4 + r;
                float rg = sigmoidf_(ar[r] + brc);
                float zg = sigmoidf_(az[r] + bzc);
                float ng = tanhf_(an[r] + bgn + rg * (ah[r] + bhn));
                float o = (1.f - zg) * ng + zg * h4[r];
                __builtin_nontemporal_store(o, &Lout[row * DIM + col]);
                if (do_mir) Lmir[row * DIM + col] = (_Float16)o;
            }
        }
    }
}

// ---------------- weight-stationary message MLP, both node types ----------------
__global__ __launch_bounds__(512, 4) void mlp_both_ws(
    const _Float16* __restrict__ XL, const _Float16* __restrict__ lW1, const float* __restrict__ lB1,
    const _Float16* __restrict__ lW2, const float* __restrict__ lB2, _Float16* __restrict__ MsgL,
    int LTiles, int LBLK,
    const _Float16* __restrict__ XC, const _Float16* __restrict__ cW1, const float* __restrict__ cB1,
    const _Float16* __restrict__ cW2, const float* __restrict__ cB2, _Float16* __restrict__ MsgC,
    int CTiles)
{
    __shared__ _Float16 hid[2][16][136];
    const int lane = threadIdx.x & 63;
    const int wave = threadIdx.x >> 6;
    const int l15 = lane & 15;
    const int kg  = lane >> 4;
    const int col = wave * 16 + l15;

    const _Float16 *X, *W1, *W2; const float *B1p, *B2p; _Float16* Msg;
    int tiles, t0, stride;
    if ((int)blockIdx.x < LBLK) {
        X = XL; W1 = lW1; B1p = lB1; W2 = lW2; B2p = lB2; Msg = MsgL;
        tiles = LTiles; t0 = blockIdx.x; stride = LBLK;
    } else {
        X = XC; W1 = cW1; B1p = cB1; W2 = cW2; B2p = cB2; Msg = MsgC;
        tiles = CTiles; t0 = blockIdx.x - LBLK; stride = gridDim.x - LBLK;
    }
    f16x8 w1[4], w2[4];
    #pragma unroll
    for (int kk = 0; kk < 4; ++kk) {
        w1[kk] = *(const f16x8*)(W1 + (size_t)col * DIM + kg * 8 + kk * 32);
        w2[kk] = *(const f16x8*)(W2 + (size_t)col * DIM + kg * 8 + kk * 32);
    }
    const float b1 = B1p[col], b2 = B2p[col];
    int buf = 0;
    for (int tile = t0; tile < tiles; tile += stride) {
        const size_t r0 = (size_t)tile * 16;
        f16x8 xa[4];
        const _Float16* xp = X + (r0 + l15) * DIM + kg * 8;
        #pragma unroll
        for (int kk = 0; kk < 4; ++kk) xa[kk] = *(const f16x8*)(xp + kk * 32);
        f32x4 a1 = {0,0,0,0};
        #pragma unroll
        for (int kk = 0; kk < 4; ++kk) a1 = MFMA16(xa[kk], w1[kk], a1);
        #pragma unroll
        for (int r = 0; r < 4; ++r) {
            float v = a1[r] + b1;
            hid[buf][kg * 4 + r][col] = (_Float16)(v > 0.f ? v : 0.f);
        }
        __syncthreads();
        f16x8 h2[4];
        #pragma unroll
        for (int kk = 0; kk < 4; ++kk)
            h2[kk] = *(const f16x8*)(&hid[buf][l15][kk * 32 + kg * 8]);
        f32x4 a2 = {0,0,0,0};
        #pragma unroll
        for (int kk = 0; kk < 4; ++kk) a2 = MFMA16(h2[kk], w2[kk], a2);
        #pragma unroll
        for (int r = 0; r < 4; ++r)
            Msg[(r0 + kg * 4 + r) * DIM + col] = (_Float16)(a2[r] + b2);
        buf ^= 1;
    }
}

extern "C" void kernel_launch(void* const* d_in, const int* in_sizes, int n_in,
                              void* d_out, int out_size, void* d_ws, size_t ws_size,
                              hipStream_t stream)
{
    const int*   l_edge = (const int*)d_in[2];
    const int*   c_edge = (const int*)d_in[3];
    const float* l_emb0 = (const float*)d_in[4];
    const float* c_emb0 = (const float*)d_in[5];
    const float* l2c_w1 = (const float*)d_in[6];
    const float* l2c_b1 = (const float*)d_in[7];
    const float* l2c_w2 = (const float*)d_in[8];
    const float* l2c_b2 = (const float*)d_in[9];
    const float* c2l_w1 = (const float*)d_in[10];
    const float* c2l_b1 = (const float*)d_in[11];
    const float* c2l_w2 = (const float*)d_in[12];
    const float* c2l_b2 = (const float*)d_in[13];
    const float* c_w_ih = (const float*)d_in[14];
    const float* c_w_hh = (const float*)d_in[15];
    const float* c_b_ih = (const float*)d_in[16];
    const float* c_b_hh = (const float*)d_in[17];
    const float* l_w_ih = (const float*)d_in[18];
    const float* l_w_hh = (const float*)d_in[19];
    const float* l_b_ih = (const float*)d_in[20];
    const float* l_b_hh = (const float*)d_in[21];

    const int n_edges = in_sizes[2];
    const int Lsz = in_sizes[4] / DIM;   // 80000
    const int Csz = in_sizes[5] / DIM;   // 160000

    float* OUT_L = (float*)d_out;                                  // (5, Lsz, 128)
    float* OUT_C = OUT_L + (size_t)(NITERS + 1) * Lsz * DIM;       // (5, Csz, 128)

    char* wsp = (char*)d_ws;
    auto carve = [&](size_t bytes) -> void* {
        void* p = (void*)wsp;
        wsp += (bytes + 255) & ~(size_t)255;
        return p;
    };
    _Float16* c_msg    = (_Float16*)carve((size_t)Csz * DIM * 2);
    _Float16* l_msg    = (_Float16*)carve((size_t)Lsz * DIM * 2);
    _Float16* l2c_aggr = (_Float16*)carve((size_t)Csz * DIM * 2);
    _Float16* c2l_aggr = (_Float16*)carve((size_t)Lsz * DIM * 2);
    _Float16* Ch0      = (_Float16*)carve((size_t)Csz * DIM * 2);
    _Float16* Ch1      = (_Float16*)carve((size_t)Csz * DIM * 2);
    _Float16* Lh0      = (_Float16*)carve((size_t)Lsz * DIM * 2);
    _Float16* Lh1      = (_Float16*)carve((size_t)Lsz * DIM * 2);
    int* deg_c = (int*)carve((size_t)(Csz)     * 4);   // deg_c|deg_l|cur_c|cur_l contiguous: one memset
    int* deg_l = (int*)carve((size_t)(Lsz)     * 4);
    int* cur_c = (int*)carve((size_t)(Csz)     * 4);
    int* cur_l = (int*)carve((size_t)(Lsz)     * 4);
    int* rs_c  = (int*)carve((size_t)(Csz + 1) * 4);
    int* rs_l  = (int*)carve((size_t)(Lsz + 1) * 4);
    int* csr_c = (int*)carve((size_t)n_edges   * 4);
    int* csr_l = (int*)carve((size_t)n_edges   * 4);
    int* bsum_c = (int*)carve(256 * 4);
    int* bsum_l = (int*)carve(256 * 4);
    _Float16* hw_l2c1 = (_Float16*)carve((size_t)DIM * DIM * 2);
    _Float16* hw_l2c2 = (_Float16*)carve((size_t)DIM * DIM * 2);
    _Float16* hw_c2l1 = (_Float16*)carve((size_t)DIM * DIM * 2);
    _Float16* hw_c2l2 = (_Float16*)carve((size_t)DIM * DIM * 2);
    _Float16* hw_cih  = (_Float16*)carve((size_t)3 * DIM * DIM * 2);
    _Float16* hw_chh  = (_Float16*)carve((size_t)3 * DIM * DIM * 2);
    _Float16* hw_lih  = (_Float16*)carve((size_t)3 * DIM * 2 * DIM * 2);
    _Float16* hw_lhh  = (_Float16*)carve((size_t)3 * DIM * DIM * 2);

    {
        ConvDesc cds[8] = {
            { l2c_w1, hw_l2c1, DIM * DIM }, { l2c_w2, hw_l2c2, DIM * DIM },
            { c2l_w1, hw_c2l1, DIM * DIM }, { c2l_w2, hw_c2l2, DIM * DIM },
            { c_w_ih, hw_cih, 3 * DIM * DIM }, { c_w_hh, hw_chh, 3 * DIM * DIM },
            { l_w_ih, hw_lih, 3 * DIM * 2 * DIM }, { l_w_hh, hw_lhh, 3 * DIM * DIM },
        };
        conv8_kernel<<<dim3(384, 8), 256, 0, stream>>>(cds[0], cds[1], cds[2], cds[3],
                                                       cds[4], cds[5], cds[6], cds[7]);
    }

    init_state_kernel<<<(Lsz * DIM / 4 + 255) / 256, 256, 0, stream>>>(l_emb0, OUT_L, Lh0, Lsz * DIM / 4);
    init_state_kernel<<<(Csz * DIM / 4 + 255) / 256, 256, 0, stream>>>(c_emb0, OUT_C, Ch0, Csz * DIM / 4);

    // ---- CSR build (both directions) ----
    hipMemsetAsync(deg_c, 0, (size_t)(2 * Csz + 2 * Lsz) * 4, stream);

    const int eb = (n_edges + 255) / 256;
    hist_both<<<2 * eb, 256, 0, stream>>>(c_edge, deg_c, l_edge, deg_l, n_edges, eb);

    const int nb_c = (Csz + 1023) / 1024;
    const int nb_l = (Lsz + 1023) / 1024;
    scan_reduce_both<<<nb_c + nb_l, 256, 0, stream>>>(deg_c, bsum_c, Csz, nb_c, deg_l, bsum_l, Lsz);
    scan_blocksums_both<<<2, 256, 0, stream>>>(bsum_c, nb_c, bsum_l, nb_l);
    scan_write_both<<<nb_c + nb_l, 256, 0, stream>>>(deg_c, bsum_c, rs_c, Csz, nb_c, deg_l, bsum_l, rs_l, Lsz);
    set2_kernel<<<1, 1, 0, stream>>>(rs_c + Csz, rs_l + Lsz, n_edges);
    fill_both<<<2 * eb, 256, 0, stream>>>(c_edge, l_edge, rs_c, cur_c, csr_c, rs_l, cur_l, csr_l, n_edges, eb);

    const int LTiles = Lsz / 16, CTiles = Csz / 16;
    const int MLP_LBLK = 340, MLP_GRID = 1024;
    const int GRU_CBLK = 150, GRU_GRID = 256;
    const int GATH_BLKA = (Csz + 3) / 4;
    const int GATH_GRID = GATH_BLKA + (Lsz + 3) / 4;

    // prologue messages from initial state
    mlp_both_ws<<<MLP_GRID, 512, 0, stream>>>(Lh0, hw_l2c1, l2c_b1, hw_l2c2, l2c_b2, l_msg, LTiles, MLP_LBLK,
                                              Ch0, hw_c2l1, c2l_b1, hw_c2l2, c2l_b2, c_msg, CTiles);

    for (int t = 0; t < NITERS; ++t) {
        float* Lt1 = OUT_L + (size_t)(t + 1) * Lsz * DIM;
        float* Ct1 = OUT_C + (size_t)(t + 1) * Csz * DIM;
        const _Float16* Lm = (t & 1) ? Lh1 : Lh0;
        const _Float16* Cm = (t & 1) ? Ch1 : Ch0;
        _Float16* Lm1 = (t & 1) ? Lh0 : Lh1;
        _Float16* Cm1 = (t & 1) ? Ch0 : Ch1;
        const int do_mir = (t < NITERS - 1) ? 1 : 0;

        gather_both<<<GATH_GRID, 256, 0, stream>>>(l_msg, rs_c, csr_c, l2c_aggr, Csz, GATH_BLKA,
                                                   c_msg, rs_l, csr_l, c2l_aggr, Lsz);
        gru_both_ws<<<GRU_GRID, 512, 0, stream>>>(l2c_aggr, Cm, hw_cih, hw_chh, c_b_ih, c_b_hh,
                                                  Ct1, Cm1, CTiles, GRU_CBLK,
                                                  c2l_aggr, Lm, hw_lih, hw_lhh, l_b_ih, l_b_hh,
                                                  Lt1, Lm1, LTiles, do_mir);
        if (t < NITERS - 1)
            mlp_both_ws<<<MLP_GRID, 512, 0, stream>>>(Lm1, hw_l2c1, l2c_b1, hw_l2c2, l2c_b2, l_msg, LTiles, MLP_LBLK,
                                                      Cm1, hw_c2l1, c2l_b1, hw_c2l2, c2l_b2, c_msg, CTiles);
    }
}